// Round 2
// baseline (835.099 us; speedup 1.0000x reference)
//
#include <hip/hip_runtime.h>

// Problem constants (B=32, d=512, T=2048)
#define BB     32
#define DD     512
#define FOURD  2048
#define FIVED  2560
#define TT     2048
#define TV     (TT / 4)   // 512 float4 per row
#define FSPLIT 10         // 8 G-splits + 2 m-splits, 256 virtual f-rows each
#define ROWS   256        // f-rows per split

// ---------------------------------------------------------------------------
// Stage 1: partial dual logit reduction.
// Grid: (T/256, FSPLIT, B) = (8, 10, 32) = 2560 blocks (~10/CU -> high occ).
// Block: 256 threads = 4 waves. Wave w handles f-rows [split*256 + w*64, +64),
// lanes = 64 consecutive float4 along t (1 KB/row, single coalesced segment).
// Splits 0..7 read G (feeds both p1 and p2); splits 8..9 read m1 (p1) and
// m2 (p2). G/m1/m2 each read exactly once -> 805 MB total mandatory traffic.
// Partials written to ws[b][which][split][t] (5.24 MB).
// ---------------------------------------------------------------------------
__global__ __launch_bounds__(256, 4) void partial_kernel(
    const float* __restrict__ G,
    const float* __restrict__ m1,
    const float* __restrict__ m2,
    const float* __restrict__ wp1,
    const float* __restrict__ wp2,
    float* __restrict__ ws)
{
    __shared__ float s_w1[ROWS];
    __shared__ float s_w2[ROWS];
    __shared__ float4 red1[4][64];
    __shared__ float4 red2[4][64];

    const int tid   = threadIdx.x;
    const int tc    = blockIdx.x;   // t-chunk: 0..7, 256 t each
    const int ys    = blockIdx.y;   // f-split: 0..9
    const int b     = blockIdx.z;
    const int fbase = ys * ROWS;    // virtual feature base

    if (tid < ROWS) {
        s_w1[tid] = wp1[fbase + tid];
        s_w2[tid] = wp2[fbase + tid];
    }
    __syncthreads();

    const int tg = tid & 63;        // lane: float4 index within t-chunk
    const int fp = tid >> 6;        // wave id 0..3 = f-part
    const int tv = tc * 64 + tg;    // float4 column index

    float4 acc1 = make_float4(0.f, 0.f, 0.f, 0.f);
    float4 acc2 = make_float4(0.f, 0.f, 0.f, 0.f);

    if (ys < 8) {
        // G region: rows fbase .. fbase+255 of G; one load feeds both outputs.
        const float4* Gv = (const float4*)(G + (size_t)b * FOURD * TT);
        const int r0 = fbase + fp * 64;
        #pragma unroll 8
        for (int i = 0; i < 64; ++i) {
            const float4 g = Gv[(size_t)(r0 + i) * TV + tv];
            const float w1 = s_w1[fp * 64 + i];   // wave-uniform -> broadcast
            const float w2 = s_w2[fp * 64 + i];
            acc1.x += w1 * g.x; acc1.y += w1 * g.y; acc1.z += w1 * g.z; acc1.w += w1 * g.w;
            acc2.x += w2 * g.x; acc2.y += w2 * g.y; acc2.z += w2 * g.z; acc2.w += w2 * g.w;
        }
    } else {
        // m region: rows (fbase-2048) .. +255 of m1 (for p1) and m2 (for p2).
        const float4* m1v = (const float4*)(m1 + (size_t)b * DD * TT);
        const float4* m2v = (const float4*)(m2 + (size_t)b * DD * TT);
        const int r0 = (fbase - FOURD) + fp * 64;
        #pragma unroll 4
        for (int i = 0; i < 64; ++i) {
            const float4 a = m1v[(size_t)(r0 + i) * TV + tv];
            const float4 c = m2v[(size_t)(r0 + i) * TV + tv];
            const float w1 = s_w1[fp * 64 + i];
            const float w2 = s_w2[fp * 64 + i];
            acc1.x += w1 * a.x; acc1.y += w1 * a.y; acc1.z += w1 * a.z; acc1.w += w1 * a.w;
            acc2.x += w2 * c.x; acc2.y += w2 * c.y; acc2.z += w2 * c.z; acc2.w += w2 * c.w;
        }
    }

    red1[fp][tg] = acc1;
    red2[fp][tg] = acc2;
    __syncthreads();

    // Cross-wave reduce: threads 0..63 -> p1, 64..127 -> p2.
    if (tid < 128) {
        const int which = tid >> 6;
        const int g     = tid & 63;
        float4 s = make_float4(0.f, 0.f, 0.f, 0.f);
        #pragma unroll
        for (int p = 0; p < 4; ++p) {
            const float4 v = which ? red2[p][g] : red1[p][g];
            s.x += v.x; s.y += v.y; s.z += v.z; s.w += v.w;
        }
        float4* o = (float4*)ws
                  + ((size_t)b * 2 * FSPLIT + (size_t)which * FSPLIT + ys) * TV
                  + tc * 64 + g;
        *o = s;
    }
}

// ---------------------------------------------------------------------------
// Stage 2: reduce FSPLIT partials + row softmax. One block per (b, which).
// 64 blocks x 256 threads, 8 t's per thread. ~5.2 MB read, 0.5 MB write.
// ---------------------------------------------------------------------------
__global__ __launch_bounds__(256) void reduce_softmax_kernel(
    const float* __restrict__ ws, float* __restrict__ out)
{
    const int b     = blockIdx.x >> 1;
    const int which = blockIdx.x & 1;
    const int tid   = threadIdx.x;
    const float* base = ws + ((size_t)b * 2 * FSPLIT + (size_t)which * FSPLIT) * TT;

    float v[8];
    float mx = -INFINITY;
    #pragma unroll
    for (int i = 0; i < 8; ++i) {
        const int t = tid + i * 256;
        float s = 0.f;
        #pragma unroll
        for (int p = 0; p < FSPLIT; ++p) s += base[(size_t)p * TT + t];
        v[i] = s;
        mx = fmaxf(mx, s);
    }

    #pragma unroll
    for (int off = 32; off > 0; off >>= 1)
        mx = fmaxf(mx, __shfl_xor(mx, off, 64));

    __shared__ float sred[4];
    const int wave = tid >> 6;
    if ((tid & 63) == 0) sred[wave] = mx;
    __syncthreads();
    if (tid == 0)
        sred[0] = fmaxf(fmaxf(sred[0], sred[1]), fmaxf(sred[2], sred[3]));
    __syncthreads();
    mx = sred[0];
    __syncthreads();

    float sum = 0.f;
    #pragma unroll
    for (int i = 0; i < 8; ++i) {
        v[i] = __expf(v[i] - mx);
        sum += v[i];
    }
    #pragma unroll
    for (int off = 32; off > 0; off >>= 1)
        sum += __shfl_xor(sum, off, 64);
    if ((tid & 63) == 0) sred[wave] = sum;
    __syncthreads();
    if (tid == 0)
        sred[0] = sred[0] + sred[1] + sred[2] + sred[3];
    __syncthreads();
    const float inv = 1.0f / sred[0];

    float* p = out + ((size_t)b * 2 + which) * TT;
    #pragma unroll
    for (int i = 0; i < 8; ++i)
        p[tid + i * 256] = v[i] * inv;
}

extern "C" void kernel_launch(void* const* d_in, const int* in_sizes, int n_in,
                              void* d_out, int out_size, void* d_ws, size_t ws_size,
                              hipStream_t stream) {
    const float* G   = (const float*)d_in[0];
    const float* m1  = (const float*)d_in[1];
    const float* m2  = (const float*)d_in[2];
    const float* wp1 = (const float*)d_in[3];
    const float* wp2 = (const float*)d_in[4];
    float* out = (float*)d_out;
    float* ws  = (float*)d_ws;

    dim3 grid1(TT / 256, FSPLIT, BB);
    partial_kernel<<<grid1, 256, 0, stream>>>(G, m1, m2, wp1, wp2, ws);
    reduce_softmax_kernel<<<BB * 2, 256, 0, stream>>>(ws, out);
}